// Round 12
// baseline (2661.940 us; speedup 1.0000x reference)
//
#include <hip/hip_runtime.h>
#include <cmath>

// ---------------- problem constants ----------------
#define S_   512
#define Z_   514            // SD + H
#define WUC  516            // WU_w cols: [x(2) | u(2) | h(512)]

// output float offsets
#define OUT_ZF   67371008   // B*S*Z
#define OUT_CZF  67502592   // + B*Z
#define OUT_COEF 67634176   // + B*Z

// ---------------- workspace layout ----------------
// img: [slot(4)][grp(16)] x 16KB f16 image [16 rows][512 units]; 1MB total.
// memset 0xFF at launch = f16 NaN sentinel (h is always finite).
#define IMG_BYTES 16384

typedef __attribute__((ext_vector_type(4))) float f32x4;
typedef __attribute__((ext_vector_type(4))) unsigned u32x4;
typedef __attribute__((ext_vector_type(8))) _Float16 f16x8;

__device__ __forceinline__ f32x4 MF16(f16x8 a, f16x8 b, f32x4 c) {
  return __builtin_amdgcn_mfma_f32_16x16x32_f16(a, b, c, 0, 0, 0);
}
// system-scope (sc0 sc1) coherent ops — round-2/4/6/10-proven encoding
__device__ __forceinline__ u32x4 ld16c(const void* p) {
  u32x4 r;
  asm volatile("global_load_dwordx4 %0, %1, off sc0 sc1" : "=v"(r) : "v"(p));
  return r;
}
__device__ __forceinline__ void st16c(void* p, u32x4 v) {
  asm volatile("global_store_dwordx4 %0, %1, off sc0 sc1" :: "v"(p), "v"(v) : "memory");
}
// chunk ready: no dword still holds the poison pattern in its low half
// (publish stores are 16B aligned exactly on consumer chunk boundaries;
// dword-atomicity makes each dword all-poison or all-data)
__device__ __forceinline__ bool rdy(u32x4 v) {
  unsigned b = (unsigned)((v[0] & 0xFFFFu) == 0xFFFFu) |
               (unsigned)((v[1] & 0xFFFFu) == 0xFFFFu) |
               (unsigned)((v[2] & 0xFFFFu) == 0xFFFFu) |
               (unsigned)((v[3] & 0xFFFFu) == 0xFFFFu);
  return b == 0u;
}
__device__ __forceinline__ float sigm(float x)  { return 1.f / (1.f + __expf(-x)); }
__device__ __forceinline__ float ftanh(float x) { return 2.f / (1.f + __expf(-2.f * x)) - 1.f; }

// cscr swizzled index (R6-proven, SQ_LDS_BANK_CONFLICT = 0)
__device__ __forceinline__ int crow(int row) { return row * 112; }
__device__ __forceinline__ int cxor(int row) { return ((row >> 2) & 1) << 4; }

// self-validating spin on 4 chunks; rule-#18 fence after every vmcnt drain
#define SPIN4(P0, P1, P2, P3, BASE)                                          \
  {                                                                          \
    bool ok0 = false, ok1 = false, ok2 = false, ok3 = false;                 \
    for (;;) {                                                               \
      if (!ok0) P0 = ld16c((BASE) + 0);                                      \
      if (!ok1) P1 = ld16c((BASE) + 64);                                     \
      if (!ok2) P2 = ld16c((BASE) + 128);                                    \
      if (!ok3) P3 = ld16c((BASE) + 192);                                    \
      asm volatile("s_waitcnt vmcnt(0)" ::: "memory");                       \
      __builtin_amdgcn_sched_barrier(0);                                     \
      ok0 = rdy(P0); ok1 = rdy(P1); ok2 = rdy(P2); ok3 = rdy(P3);            \
      if (ok0 && ok1 && ok2 && ok3) break;                                   \
      __builtin_amdgcn_s_sleep(1);                                           \
    }                                                                        \
    __builtin_amdgcn_sched_barrier(0);                                       \
  }

// grid: 512 blocks = grp(16) x ub(32); block: 256 threads = 4 waves (one per K-128).
// 2 blocks/CU from DIFFERENT groups -> two independent recurrence streams per CU:
// one stream's spin idle hides under the other's compute (m114 co-scheduling).
// Co-residency of all 512 is capacity-guaranteed: launch_bounds(256,2) caps regs
// at the 8-wave/CU budget (same per-wave footprint R6 proved fits), LDS 28.7KB x2.
__global__ __launch_bounds__(256, 2) void lstm_persist(
    const float* __restrict__ rnn, const float* __restrict__ tau,
    const float* __restrict__ z0,  const float* __restrict__ c0,
    const float* __restrict__ wuw, const float* __restrict__ wub,
    const float* __restrict__ awp, const float* __restrict__ abp,
    const float* __restrict__ whw, const float* __restrict__ whb,
    const float* __restrict__ Amat, const float* __restrict__ Bmat,
    float* __restrict__ out, char* __restrict__ img)
{
  __shared__ float cscr[64 * 112];   // 28,672 B, swizzled (gates 0..63, dots 64..67)

  const int tid = threadIdx.x;
  const int blk = blockIdx.x;
  const int grp = blk >> 5;        // group -> rows [grp*16, grp*16+16)
  const int ub  = blk & 31;        // unit block -> units [ub*16, ub*16+16)
  const int j0  = ub * 16;
  const int lane = tid & 63;
  const int kq   = tid >> 6;       // wave = K chunk of 128
  const int ln15 = lane & 15;
  const int lq   = lane >> 4;
  const int row_l = tid >> 4;      // pointwise row 0..15
  const int unit  = tid & 15;      // pointwise unit 0..15
  const int rg    = grp * 16 + row_l;
  const int ju    = j0 + unit;

  // ---------------- prologue: weights -> registers (split f16, R6 pattern) ----------------
  f16x8 bHf[4][5], bLf[4][5];
#pragma unroll
  for (int s = 0; s < 4; ++s) {
    const int kbase = kq * 128 + s * 32 + lq * 8;
#pragma unroll
    for (int n = 0; n < 4; ++n) {
      const float* wp = wuw + (size_t)(n * 512 + j0 + ln15) * WUC + 4 + kbase;
      f16x8 vh, vl;
#pragma unroll
      for (int e = 0; e < 8; ++e) {
        float w = wp[e];
        _Float16 hi = (_Float16)w;
        vh[e] = hi;
        vl[e] = (_Float16)(w - (float)hi);
      }
      bHf[s][n] = vh; bLf[s][n] = vl;
    }
    {
      f16x8 vh, vl;
#pragma unroll
      for (int e = 0; e < 8; ++e) {   // n=4: [alpha_w ; Wh_w ; zeros] tile
        int k = kbase + e;
        float w = 0.f;
        if (ln15 < 2)      w = awp[ln15 * 512 + k];
        else if (ln15 < 4) w = whw[(ln15 - 2) * 512 + k];
        _Float16 hi = (_Float16)w;
        vh[e] = hi;
        vl[e] = (_Float16)(w - (float)hi);
      }
      bHf[s][4] = vh; bLf[s][4] = vl;
    }
  }
  // small params + per-thread pointwise weights (registers)
  const float pA00 = Amat[0], pA01 = Amat[1], pA10 = Amat[2], pA11 = Amat[3];
  const float pB0 = Bmat[0], pB1 = Bmat[1];
  const float pab0 = abp[0], pab1 = abp[1], pwb0 = whb[0], pwb1 = whb[1];
  float gb_[4], gw_[4][4];
#pragma unroll
  for (int n = 0; n < 4; ++n) {
    const int r = n * 512 + ju;
    gb_[n] = wub[r];
    const float* wr = wuw + (size_t)r * WUC;
    gw_[n][0] = wr[0]; gw_[n][1] = wr[1]; gw_[n][2] = wr[2]; gw_[n][3] = wr[3];
  }
  float px0 = z0[(size_t)rg * Z_ + 0], px1 = z0[(size_t)rg * Z_ + 1];
  float c_state = c0[(size_t)rg * Z_ + 2 + ju];
  float u0_prev = 0.f, tau_prev = 0.f, hval = 0.f;
  float alc0 = 0.f, alc1 = 0.f;

  // publish z0 h-slice into slot 3 (16B packed via 3 shfl rounds, R11-verified)
  {
    float hv = z0[(size_t)rg * Z_ + 2 + ju];
    unsigned hz = (unsigned)__builtin_bit_cast(unsigned short, (_Float16)hv);
    unsigned v0 = hz | ((unsigned)__shfl_xor((int)hz, 1) << 16);
    unsigned v1 = (unsigned)__shfl_xor((int)v0, 2);
    unsigned v2 = (unsigned)__shfl_xor((int)v0, 4);
    unsigned v3 = (unsigned)__shfl_xor((int)v1, 4);
    if ((unit & 7) == 0) {
      u32x4 d = {v0, v1, v2, v3};
      st16c(img + (size_t)(3 * 16 + grp) * IMG_BYTES + row_l * 1024 + ju * 2, d);
    }
  }
  __syncthreads();

  const int fragbase = ln15 * 1024 + kq * 256 + lq * 16;

  // ---------------- main loop ----------------
  for (int t = 0; t < S_; ++t) {
    const float u0v = rnn[((size_t)rg * S_ + t) * 2 + 0];
    const float u1v = rnn[((size_t)rg * S_ + t) * 2 + 1];
    const float tv  = tau[(size_t)rg * S_ + t];

    // deferred harness stores — acks complete in the spin shadow
    if (t >= 1)
      __builtin_nontemporal_store(hval, out + ((size_t)rg * S_ + (t - 1)) * Z_ + 2 + ju);
    if (t >= 2 && ub == 0 && unit == 0) {
      const size_t ob = ((size_t)rg * S_ + (t - 2)) * Z_;
      __builtin_nontemporal_store(px0, out + ob + 0);
      __builtin_nontemporal_store(px1, out + ob + 1);
      const size_t cb = OUT_COEF + ((size_t)rg * S_ + (t - 2)) * 2;
      __builtin_nontemporal_store(alc0, out + cb + 0);
      __builtin_nontemporal_store(alc1, out + cb + 1);
    }

    // self-validating spin: the poll IS the fragment load (slot (t-1)&3)
    const char* baseR = img + (size_t)(((t + 3) & 3) * 16 + grp) * IMG_BYTES + fragbase;
    u32x4 A0, A1, A2, A3;
    SPIN4(A0, A1, A2, A3, baseR);

    // GEMM: 4 ksteps x (4 gates + dots) x (hi+lo) = 40 MFMA (R6 pattern, M=16)
    f32x4 a0 = {0,0,0,0}, a1 = {0,0,0,0}, a2 = {0,0,0,0}, a3 = {0,0,0,0}, a4 = {0,0,0,0};
#pragma unroll
    for (int s = 0; s < 4; ++s) {
      u32x4 As = (s == 0) ? A0 : (s == 1) ? A1 : (s == 2) ? A2 : A3;
      f16x8 ah = __builtin_bit_cast(f16x8, As);
      a0 = MF16(ah, bHf[s][0], a0); a0 = MF16(ah, bLf[s][0], a0);
      a1 = MF16(ah, bHf[s][1], a1); a1 = MF16(ah, bLf[s][1], a1);
      a2 = MF16(ah, bHf[s][2], a2); a2 = MF16(ah, bLf[s][2], a2);
      a3 = MF16(ah, bHf[s][3], a3); a3 = MF16(ah, bLf[s][3], a3);
      a4 = MF16(ah, bHf[s][4], a4); a4 = MF16(ah, bLf[s][4], a4);
    }
    {
      const int Rb = kq * 16 + lq * 4;
#pragma unroll
      for (int r = 0; r < 4; ++r) {
        const int row = Rb + r;
        float* cp = cscr + crow(row);
        const int xb = cxor(row);
        cp[(0 * 16 ^ xb) + ln15] = a0[r];
        cp[(1 * 16 ^ xb) + ln15] = a1[r];
        cp[(2 * 16 ^ xb) + ln15] = a2[r];
        cp[(3 * 16 ^ xb) + ln15] = a3[r];
        cp[(4 * 16 ^ xb) + ln15] = a4[r];
      }
    }
    __syncthreads();   // B1

    // gate sums + alpha/Wh dots: 4 ascending K-128 partials (same tree as R6)
    float g0 = 0, g1 = 0, g2 = 0, g3 = 0, d0 = 0, d1 = 0, d2 = 0, d3 = 0;
#pragma unroll
    for (int q = 0; q < 4; ++q) {
      const int row = q * 16 + row_l;
      const float* cp = cscr + crow(row);
      const int xb = cxor(row);
      g0 += cp[(0 * 16 ^ xb) + unit]; g1 += cp[(1 * 16 ^ xb) + unit];
      g2 += cp[(2 * 16 ^ xb) + unit]; g3 += cp[(3 * 16 ^ xb) + unit];
      const f32x4 dv = *(const f32x4*)(cp + (64 ^ xb));
      d0 += dv[0]; d1 += dv[1]; d2 += dv[2]; d3 += dv[3];
    }
    // finalize x(t-1) (replicated per-thread, uniform within each row group)
    if (t > 0) {
      const float al0 = sigm(d0 + pab0), al1 = sigm(d1 + pab1);
      const float wh0 = d2 + pwb0, wh1 = d3 + pwb1;
      const float xm0 = px0 + tau_prev * (pA00 * px0 + pA01 * px1 + pB0 * u0_prev);
      const float xm1 = px1 + tau_prev * (pA10 * px0 + pA11 * px1 + pB1 * u0_prev);
      px0 = al0 * xm0 + (1.f - al0) * wh0;
      px1 = al1 * xm1 + (1.f - al1) * wh1;
      alc0 = al0; alc1 = al1;
    }
    // pointwise LSTM
    g0 += gb_[0] + px0 * gw_[0][0] + px1 * gw_[0][1] + u0v * gw_[0][2] + u1v * gw_[0][3];
    g1 += gb_[1] + px0 * gw_[1][0] + px1 * gw_[1][1] + u0v * gw_[1][2] + u1v * gw_[1][3];
    g2 += gb_[2] + px0 * gw_[2][0] + px1 * gw_[2][1] + u0v * gw_[2][2] + u1v * gw_[2][3];
    g3 += gb_[3] + px0 * gw_[3][0] + px1 * gw_[3][1] + u0v * gw_[3][2] + u1v * gw_[3][3];
    const float ci = sigm(g0), cf = sigm(g1), co = sigm(g3);
    c_state = cf * c_state + ci * ftanh(g2);
    hval = co * ftanh(c_state);
    u0_prev = u0v; tau_prev = tv;

    // publish h(t) -> slot t&3 (16B packed, fire-and-forget)
    {
      unsigned hz = (unsigned)__builtin_bit_cast(unsigned short, (_Float16)hval);
      unsigned v0 = hz | ((unsigned)__shfl_xor((int)hz, 1) << 16);
      unsigned v1 = (unsigned)__shfl_xor((int)v0, 2);
      unsigned v2 = (unsigned)__shfl_xor((int)v0, 4);
      unsigned v3 = (unsigned)__shfl_xor((int)v1, 4);
      if ((unit & 7) == 0) {
        u32x4 d = {v0, v1, v2, v3};
        st16c(img + (size_t)((t & 3) * 16 + grp) * IMG_BYTES + row_l * 1024 + ju * 2, d);
      }
    }
    // wave 0 re-poisons this block's 512B slice of slot (t+2)&3 (dead h(t-2));
    // drained by wave 0's next spin vmcnt(0), ordered before t+2's publish by B1
    if (kq == 0 && lane < 32) {
      u32x4 poison = {~0u, ~0u, ~0u, ~0u};
      st16c(img + (size_t)(((t + 2) & 3) * 16 + grp) * IMG_BYTES
                + (lane >> 1) * 1024 + j0 * 2 + (lane & 1) * 16, poison);
    }
    __syncthreads();   // B2: full drain — producer self-throttle keeping the
                       // group phase-locked (R7/R8/R9: removing it costs ~+300us)
  }

  // ---------------- tail: pending stores + alpha/x for t = 511 ----------------
  __builtin_nontemporal_store(hval, out + ((size_t)rg * S_ + 511) * Z_ + 2 + ju);
  __builtin_nontemporal_store(hval,    out + OUT_ZF  + (size_t)rg * Z_ + 2 + ju);
  __builtin_nontemporal_store(c_state, out + OUT_CZF + (size_t)rg * Z_ + 2 + ju);
  if (ub == 0 && unit == 0) {
    const size_t ob = ((size_t)rg * S_ + 510) * Z_;
    __builtin_nontemporal_store(px0, out + ob + 0);
    __builtin_nontemporal_store(px1, out + ob + 1);
    const size_t cb = OUT_COEF + ((size_t)rg * S_ + 510) * 2;
    __builtin_nontemporal_store(alc0, out + cb + 0);
    __builtin_nontemporal_store(alc1, out + cb + 1);
  }

  // final alpha/Wh dots over h(511) (slot 511&3 = 3)
  {
    const char* baseR = img + (size_t)(3 * 16 + grp) * IMG_BYTES + fragbase;
    u32x4 A0, A1, A2, A3;
    SPIN4(A0, A1, A2, A3, baseR);
    f32x4 a4 = {0, 0, 0, 0};
#pragma unroll
    for (int s = 0; s < 4; ++s) {
      u32x4 As = (s == 0) ? A0 : (s == 1) ? A1 : (s == 2) ? A2 : A3;
      f16x8 ah = __builtin_bit_cast(f16x8, As);
      a4 = MF16(ah, bHf[s][4], a4); a4 = MF16(ah, bLf[s][4], a4);
    }
    const int Rb = kq * 16 + lq * 4;
#pragma unroll
    for (int r = 0; r < 4; ++r) {
      const int row = Rb + r;
      cscr[crow(row) + ((4 * 16) ^ cxor(row)) + ln15] = a4[r];
    }
  }
  __syncthreads();
  {
    float d0 = 0, d1 = 0, d2 = 0, d3 = 0;
#pragma unroll
    for (int q = 0; q < 4; ++q) {
      const int row = q * 16 + row_l;
      const f32x4 dv = *(const f32x4*)(cscr + crow(row) + (64 ^ cxor(row)));
      d0 += dv[0]; d1 += dv[1]; d2 += dv[2]; d3 += dv[3];
    }
    const float al0 = sigm(d0 + pab0), al1 = sigm(d1 + pab1);
    const float wh0 = d2 + pwb0, wh1 = d3 + pwb1;
    const float xm0 = px0 + tau_prev * (pA00 * px0 + pA01 * px1 + pB0 * u0_prev);
    const float xm1 = px1 + tau_prev * (pA10 * px0 + pA11 * px1 + pB1 * u0_prev);
    const float xn0 = al0 * xm0 + (1.f - al0) * wh0;
    const float xn1 = al1 * xm1 + (1.f - al1) * wh1;
    if (ub == 0 && unit == 0) {
      const size_t ob = ((size_t)rg * S_ + 511) * Z_;
      __builtin_nontemporal_store(xn0, out + ob + 0);
      __builtin_nontemporal_store(xn1, out + ob + 1);
      const size_t cb = OUT_COEF + ((size_t)rg * S_ + 511) * 2;
      __builtin_nontemporal_store(al0, out + cb + 0);
      __builtin_nontemporal_store(al1, out + cb + 1);
      __builtin_nontemporal_store(xn0, out + OUT_ZF  + (size_t)rg * Z_ + 0);
      __builtin_nontemporal_store(xn1, out + OUT_ZF  + (size_t)rg * Z_ + 1);
      __builtin_nontemporal_store(c0[(size_t)rg * Z_ + 0], out + OUT_CZF + (size_t)rg * Z_ + 0);
      __builtin_nontemporal_store(c0[(size_t)rg * Z_ + 1], out + OUT_CZF + (size_t)rg * Z_ + 1);
    }
  }
}

extern "C" void kernel_launch(void* const* d_in, const int* in_sizes, int n_in,
                              void* d_out, int out_size, void* d_ws, size_t ws_size,
                              hipStream_t stream) {
  const float* rnn  = (const float*)d_in[0];
  const float* tauP = (const float*)d_in[1];
  const float* z0   = (const float*)d_in[2];
  const float* c0   = (const float*)d_in[3];
  const float* wuw  = (const float*)d_in[4];
  const float* wub  = (const float*)d_in[5];
  const float* awp  = (const float*)d_in[6];
  const float* abp  = (const float*)d_in[7];
  const float* whw  = (const float*)d_in[8];
  const float* whb  = (const float*)d_in[9];
  const float* Amat = (const float*)d_in[10];
  const float* Bmat = (const float*)d_in[11];
  float* out = (float*)d_out;
  char* img = (char*)d_ws;   // 1 MB: 4 slots x 16 grp x 16KB

  // poison all image slots (f16 NaN sentinel) every call — captured in the graph
  hipMemsetAsync(d_ws, 0xFF, 4 * 16 * IMG_BYTES, stream);
  (void)in_sizes; (void)n_in; (void)out_size; (void)ws_size;

  hipLaunchKernelGGL(lstm_persist, dim3(512), dim3(256), 0, stream,
                     rnn, tauP, z0, c0, wuw, wub, awp, abp, whw, whb, Amat, Bmat,
                     out, img);
}

// Round 13
// 1315.085 us; speedup vs baseline: 2.0242x; 2.0242x over previous
//
#include <hip/hip_runtime.h>
#include <cmath>

// ---------------- problem constants ----------------
#define S_   512
#define Z_   514            // SD + H
#define WUC  516            // WU_w cols: [x(2) | u(2) | h(512)]

// output float offsets
#define OUT_ZF   67371008   // B*S*Z
#define OUT_CZF  67502592   // + B*Z
#define OUT_COEF 67634176   // + B*Z

// ---------------- workspace layout ----------------
// img: [slot(4)][bg(8)] x 32KB f16 image [32 rows][512 units]; 1MB total.
// Launch-time memset 0xFF poisons everything (0xFFFF = f16 NaN sentinel;
// real h / z0-h are always finite, so sentinel is unambiguous).
#define IMG_BYTES 32768

typedef __attribute__((ext_vector_type(4))) float f32x4;
typedef __attribute__((ext_vector_type(4))) unsigned u32x4;
typedef __attribute__((ext_vector_type(8))) _Float16 f16x8;

__device__ __forceinline__ f32x4 MF16(f16x8 a, f16x8 b, f32x4 c) {
  return __builtin_amdgcn_mfma_f32_16x16x32_f16(a, b, c, 0, 0, 0);
}
// system-scope (sc0 sc1) coherent ops — round-2/4/6/10-proven encoding
__device__ __forceinline__ u32x4 ld16c(const void* p) {
  u32x4 r;
  asm volatile("global_load_dwordx4 %0, %1, off sc0 sc1" : "=v"(r) : "v"(p));
  return r;
}
__device__ __forceinline__ void st16c(void* p, u32x4 v) {
  asm volatile("global_store_dwordx4 %0, %1, off sc0 sc1" :: "v"(p), "v"(v) : "memory");
}
__device__ __forceinline__ void st4c(void* p, unsigned v) {
  asm volatile("global_store_dword %0, %1, off sc0 sc1" :: "v"(p), "v"(v) : "memory");
}
// chunk ready: no dword still holds the poison pattern in its low half
// (producer 4B stores are dword-atomic: each dword is all-poison or all-data)
__device__ __forceinline__ bool rdy(u32x4 v) {
  unsigned b = (unsigned)((v[0] & 0xFFFFu) == 0xFFFFu) |
               (unsigned)((v[1] & 0xFFFFu) == 0xFFFFu) |
               (unsigned)((v[2] & 0xFFFFu) == 0xFFFFu) |
               (unsigned)((v[3] & 0xFFFFu) == 0xFFFFu);
  return b == 0u;
}
// overflow-safe fast transcendentals (inf-graceful, no NaN paths)
__device__ __forceinline__ float sigm(float x)  { return 1.f / (1.f + __expf(-x)); }
__device__ __forceinline__ float ftanh(float x) { return 2.f / (1.f + __expf(-2.f * x)) - 1.f; }

// cscr swizzled index: stride 112 floats, XOR bit4 of col with (row>>2)&1.
// Writes (rows 4 apart) and reads (rows 1 apart) both land 2-way = free.
__device__ __forceinline__ int crow(int row) { return row * 112; }
__device__ __forceinline__ int cxor(int row) { return ((row >> 2) & 1) << 4; }

// grid: 256 blocks = bg(8) x gg(32); block: 512 threads = 8 waves
__global__ __launch_bounds__(512, 2) void lstm_persist(
    const float* __restrict__ rnn, const float* __restrict__ tau,
    const float* __restrict__ z0,  const float* __restrict__ c0,
    const float* __restrict__ wuw, const float* __restrict__ wub,
    const float* __restrict__ awp, const float* __restrict__ abp,
    const float* __restrict__ whw, const float* __restrict__ whb,
    const float* __restrict__ Amat, const float* __restrict__ Bmat,
    float* __restrict__ out, char* __restrict__ img)
{
  __shared__ float cscr[8 * 16 * 112];   // 56 KB, swizzled (gates 0..63, dots 64..67)
  __shared__ float gwL[4][16][4];        // per-unit x/u weights
  __shared__ float gbL[4][16];           // per-unit bias

  const int tid = threadIdx.x;
  const int blk = blockIdx.x;
  const int bg  = blk & 7;         // batch group -> rows [bg*32, bg*32+32)
  const int gg  = blk >> 3;        // gate group  -> units [gg*16, gg*16+16)
  const int rb0 = bg * 32;
  const int j0  = gg * 16;
  const int lane = tid & 63;
  const int wv   = tid >> 6;       // wave 0..7
  const int m    = wv & 1;         // M tile (16 rows)
  const int kq   = wv >> 1;        // K quarter (128)
  const int bb   = tid >> 4;       // 0..31 local batch row (pointwise mapping)
  const int jj   = tid & 15;       // unit-in-block
  const int gb   = rb0 + bb;
  const int ln15 = lane & 15;
  const int lq   = lane >> 4;

  // ---------------- prologue: weights -> registers (single f16) ----------------
  // R13 single-variable probe: drop the lo-correction weight term (40->20 MFMA).
  // Weight rounding rel ~5e-4 (fixed) -> predicted absmax 0.005-0.015 (thr 0.069).
  f16x8 bHf[4][5];
#pragma unroll
  for (int s = 0; s < 4; ++s) {
    const int kbase = kq * 128 + s * 32 + lq * 8;
#pragma unroll
    for (int n = 0; n < 4; ++n) {
      const float* wp = wuw + (size_t)(n * 512 + j0 + ln15) * WUC + 4 + kbase;
      f16x8 vh;
#pragma unroll
      for (int e = 0; e < 8; ++e) vh[e] = (_Float16)wp[e];
      bHf[s][n] = vh;
    }
    {
      f16x8 vh;
#pragma unroll
      for (int e = 0; e < 8; ++e) {   // n=4: [alpha_w ; Wh_w ; zeros] tile
        int k = kbase + e;
        float w = 0.f;
        if (ln15 < 2)      w = awp[ln15 * 512 + k];
        else if (ln15 < 4) w = whw[(ln15 - 2) * 512 + k];
        vh[e] = (_Float16)w;
      }
      bHf[s][4] = vh;
    }
  }
  // small params
  const float pA00 = Amat[0], pA01 = Amat[1], pA10 = Amat[2], pA11 = Amat[3];
  const float pB0 = Bmat[0], pB1 = Bmat[1];
  const float pab0 = abp[0], pab1 = abp[1], pwb0 = whb[0], pwb1 = whb[1];
  if (tid < 64) {
    const int n = tid >> 4, j = tid & 15;
    const int r = n * 512 + j0 + j;
    gbL[n][j] = wub[r];
    const float* wr = wuw + (size_t)r * WUC;
    gwL[n][j][0] = wr[0]; gwL[n][j][1] = wr[1];
    gwL[n][j][2] = wr[2]; gwL[n][j][3] = wr[3];
  }
  // states (x replicated across the 16 threads of each bb-group)
  float px0 = z0[(size_t)gb * Z_ + 0], px1 = z0[(size_t)gb * Z_ + 1];
  float c_state = c0[(size_t)gb * Z_ + 2 + j0 + jj];
  float u0_prev = 0.f, tau_prev = 0.f, hval = 0.f;
  float alc0 = 0.f, alc1 = 0.f;

  // publish z0 h-slice into slot 3 ("h(-1)"), pair-packed fire-and-forget
  {
    float hv = z0[(size_t)gb * Z_ + 2 + j0 + jj];
    unsigned hz = (unsigned)__builtin_bit_cast(unsigned short, (_Float16)hv);
    unsigned ph = (unsigned)__shfl_xor((int)hz, 1);
    if ((jj & 1) == 0)
      st4c(img + (size_t)(3 * 8 + bg) * IMG_BYTES + bb * 1024 + (j0 + jj) * 2,
           hz | (ph << 16));
  }
  __syncthreads();

  const int fragbase = (m * 16 + ln15) * 1024 + kq * 256 + lq * 16;
  const int mm = bb >> 4, rr = bb & 15;

  // ---------------- main loop ----------------
  for (int t = 0; t < S_; ++t) {
    const float u0v = rnn[((size_t)gb * S_ + t) * 2 + 0];
    const float u1v = rnn[((size_t)gb * S_ + t) * 2 + 1];
    const float tv  = tau[(size_t)gb * S_ + t];

    // deferred harness stores — acks complete in the spin shadow
    if (t >= 1)
      __builtin_nontemporal_store(hval, out + ((size_t)gb * S_ + (t - 1)) * Z_ + 2 + j0 + jj);
    if (t >= 2 && gg == 0 && jj == 0) {
      const size_t ob = ((size_t)gb * S_ + (t - 2)) * Z_;
      __builtin_nontemporal_store(px0, out + ob + 0);
      __builtin_nontemporal_store(px1, out + ob + 1);
      const size_t cb = OUT_COEF + ((size_t)gb * S_ + (t - 2)) * 2;
      __builtin_nontemporal_store(alc0, out + cb + 0);
      __builtin_nontemporal_store(alc1, out + cb + 1);
    }

    // self-validating spin: the poll IS the fragment load (slot (t-1)&3).
    // RULE #18 FENCE: sched_barrier(0) after the vmcnt drain (round-6 proven).
    const char* baseR = img + (size_t)(((t + 3) & 3) * 8 + bg) * IMG_BYTES + fragbase;
    u32x4 A0, A1, A2, A3;
    {
      bool ok0 = false, ok1 = false, ok2 = false, ok3 = false;
      for (;;) {
        if (!ok0) A0 = ld16c(baseR + 0);
        if (!ok1) A1 = ld16c(baseR + 64);
        if (!ok2) A2 = ld16c(baseR + 128);
        if (!ok3) A3 = ld16c(baseR + 192);
        asm volatile("s_waitcnt vmcnt(0)" ::: "memory");
        __builtin_amdgcn_sched_barrier(0);
        ok0 = rdy(A0); ok1 = rdy(A1); ok2 = rdy(A2); ok3 = rdy(A3);
        if (ok0 && ok1 && ok2 && ok3) break;
        __builtin_amdgcn_s_sleep(1);
      }
    }
    __builtin_amdgcn_sched_barrier(0);

    f32x4 a0 = {0,0,0,0}, a1 = {0,0,0,0}, a2 = {0,0,0,0}, a3 = {0,0,0,0}, a4 = {0,0,0,0};
#pragma unroll
    for (int s = 0; s < 4; ++s) {
      u32x4 As = (s == 0) ? A0 : (s == 1) ? A1 : (s == 2) ? A2 : A3;
      f16x8 ah = __builtin_bit_cast(f16x8, As);
      a0 = MF16(ah, bHf[s][0], a0);
      a1 = MF16(ah, bHf[s][1], a1);
      a2 = MF16(ah, bHf[s][2], a2);
      a3 = MF16(ah, bHf[s][3], a3);
      a4 = MF16(ah, bHf[s][4], a4);
    }
    {
      const int Rb = (kq * 2 + m) * 16 + lq * 4;
#pragma unroll
      for (int r = 0; r < 4; ++r) {
        const int row = Rb + r;
        float* cp = cscr + crow(row);
        const int xb = cxor(row);
        cp[(0 * 16 ^ xb) + ln15] = a0[r];
        cp[(1 * 16 ^ xb) + ln15] = a1[r];
        cp[(2 * 16 ^ xb) + ln15] = a2[r];
        cp[(3 * 16 ^ xb) + ln15] = a3[r];
        cp[(4 * 16 ^ xb) + ln15] = a4[r];
      }
    }
    __syncthreads();   // B1

    // gate sums + alpha/Wh dots (dot quad is one aligned float4)
    float g0 = 0, g1 = 0, g2 = 0, g3 = 0, d0 = 0, d1 = 0, d2 = 0, d3 = 0;
#pragma unroll
    for (int q = 0; q < 4; ++q) {
      const int row = (q * 2 + mm) * 16 + rr;
      const float* cp = cscr + crow(row);
      const int xb = cxor(row);
      g0 += cp[(0 * 16 ^ xb) + jj]; g1 += cp[(1 * 16 ^ xb) + jj];
      g2 += cp[(2 * 16 ^ xb) + jj]; g3 += cp[(3 * 16 ^ xb) + jj];
      const f32x4 dv = *(const f32x4*)(cp + (64 ^ xb));
      d0 += dv[0]; d1 += dv[1]; d2 += dv[2]; d3 += dv[3];
    }
    // finalize x(t-1) (replicated per-thread, uniform within each bb-group)
    if (t > 0) {
      const float al0 = sigm(d0 + pab0), al1 = sigm(d1 + pab1);
      const float wh0 = d2 + pwb0, wh1 = d3 + pwb1;
      const float xm0 = px0 + tau_prev * (pA00 * px0 + pA01 * px1 + pB0 * u0_prev);
      const float xm1 = px1 + tau_prev * (pA10 * px0 + pA11 * px1 + pB1 * u0_prev);
      px0 = al0 * xm0 + (1.f - al0) * wh0;
      px1 = al1 * xm1 + (1.f - al1) * wh1;
      alc0 = al0; alc1 = al1;
    }
    // pointwise LSTM
    g0 += gbL[0][jj] + px0 * gwL[0][jj][0] + px1 * gwL[0][jj][1] + u0v * gwL[0][jj][2] + u1v * gwL[0][jj][3];
    g1 += gbL[1][jj] + px0 * gwL[1][jj][0] + px1 * gwL[1][jj][1] + u0v * gwL[1][jj][2] + u1v * gwL[1][jj][3];
    g2 += gbL[2][jj] + px0 * gwL[2][jj][0] + px1 * gwL[2][jj][1] + u0v * gwL[2][jj][2] + u1v * gwL[2][jj][3];
    g3 += gbL[3][jj] + px0 * gwL[3][jj][0] + px1 * gwL[3][jj][1] + u0v * gwL[3][jj][2] + u1v * gwL[3][jj][3];
    const float ci = sigm(g0), cf = sigm(g1), co = sigm(g3);
    c_state = cf * c_state + ci * ftanh(g2);
    hval = co * ftanh(c_state);
    u0_prev = u0v; tau_prev = tv;

    // publish h(t) -> slot t&3: pair-packed 4B stores, fire-and-forget
    {
      unsigned hz = (unsigned)__builtin_bit_cast(unsigned short, (_Float16)hval);
      unsigned ph = (unsigned)__shfl_xor((int)hz, 1);
      if ((jj & 1) == 0)
        st4c(img + (size_t)((t & 3) * 8 + bg) * IMG_BYTES + bb * 1024 + (j0 + jj) * 2,
             hz | (ph << 16));
    }
    // wave 0 re-poisons this block's slice of slot (t+2)&3 (holds dead h(t-2);
    // drained by wave 0's next spin vmcnt(0), ordered before t+2's publish by B1)
    if (wv == 0) {
      const int row = lane >> 1, half = lane & 1;
      u32x4 poison = {~0u, ~0u, ~0u, ~0u};
      st16c(img + (size_t)(((t + 2) & 3) * 8 + bg) * IMG_BYTES + row * 1024 + (j0 + half * 8) * 2,
            poison);
    }
    __syncthreads();   // B2: full drain — the producer self-throttle that keeps
                       // the 32-block group phase-locked (R7/R8/R9/R12: every
                       // weakening of this regressed)
  }

  // ---------------- tail: pending stores + alpha/x for t = 511 ----------------
  __builtin_nontemporal_store(hval, out + ((size_t)gb * S_ + 511) * Z_ + 2 + j0 + jj);
  __builtin_nontemporal_store(hval,    out + OUT_ZF  + (size_t)gb * Z_ + 2 + j0 + jj);
  __builtin_nontemporal_store(c_state, out + OUT_CZF + (size_t)gb * Z_ + 2 + j0 + jj);
  if (gg == 0 && jj == 0) {
    const size_t ob = ((size_t)gb * S_ + 510) * Z_;
    __builtin_nontemporal_store(px0, out + ob + 0);
    __builtin_nontemporal_store(px1, out + ob + 1);
    const size_t cb = OUT_COEF + ((size_t)gb * S_ + 510) * 2;
    __builtin_nontemporal_store(alc0, out + cb + 0);
    __builtin_nontemporal_store(alc1, out + cb + 1);
  }

  // final alpha/Wh GEMM over h(511) (slot 511&3 = 3), NaN-spin validated
  {
    const char* baseR = img + (size_t)(3 * 8 + bg) * IMG_BYTES + fragbase;
    u32x4 A0, A1, A2, A3;
    {
      bool ok0 = false, ok1 = false, ok2 = false, ok3 = false;
      for (;;) {
        if (!ok0) A0 = ld16c(baseR + 0);
        if (!ok1) A1 = ld16c(baseR + 64);
        if (!ok2) A2 = ld16c(baseR + 128);
        if (!ok3) A3 = ld16c(baseR + 192);
        asm volatile("s_waitcnt vmcnt(0)" ::: "memory");
        __builtin_amdgcn_sched_barrier(0);
        ok0 = rdy(A0); ok1 = rdy(A1); ok2 = rdy(A2); ok3 = rdy(A3);
        if (ok0 && ok1 && ok2 && ok3) break;
        __builtin_amdgcn_s_sleep(1);
      }
    }
    __builtin_amdgcn_sched_barrier(0);
    f32x4 a4 = {0,0,0,0};
#pragma unroll
    for (int s = 0; s < 4; ++s) {
      u32x4 As = (s == 0) ? A0 : (s == 1) ? A1 : (s == 2) ? A2 : A3;
      f16x8 ah = __builtin_bit_cast(f16x8, As);
      a4 = MF16(ah, bHf[s][4], a4);
    }
    const int Rb = (kq * 2 + m) * 16 + lq * 4;
#pragma unroll
    for (int r = 0; r < 4; ++r) {
      const int row = Rb + r;
      cscr[crow(row) + ((4 * 16) ^ cxor(row)) + ln15] = a4[r];
    }
  }
  __syncthreads();
  {
    float d0 = 0, d1 = 0, d2 = 0, d3 = 0;
#pragma unroll
    for (int q = 0; q < 4; ++q) {
      const int row = (q * 2 + mm) * 16 + rr;
      const f32x4 dv = *(const f32x4*)(cscr + crow(row) + (64 ^ cxor(row)));
      d0 += dv[0]; d1 += dv[1]; d2 += dv[2]; d3 += dv[3];
    }
    const float al0 = sigm(d0 + pab0), al1 = sigm(d1 + pab1);
    const float wh0 = d2 + pwb0, wh1 = d3 + pwb1;
    const float xm0 = px0 + tau_prev * (pA00 * px0 + pA01 * px1 + pB0 * u0_prev);
    const float xm1 = px1 + tau_prev * (pA10 * px0 + pA11 * px1 + pB1 * u0_prev);
    const float xn0 = al0 * xm0 + (1.f - al0) * wh0;
    const float xn1 = al1 * xm1 + (1.f - al1) * wh1;
    if (gg == 0 && jj == 0) {
      const size_t ob = ((size_t)gb * S_ + 511) * Z_;
      __builtin_nontemporal_store(xn0, out + ob + 0);
      __builtin_nontemporal_store(xn1, out + ob + 1);
      const size_t cb = OUT_COEF + ((size_t)gb * S_ + 511) * 2;
      __builtin_nontemporal_store(al0, out + cb + 0);
      __builtin_nontemporal_store(al1, out + cb + 1);
      __builtin_nontemporal_store(xn0, out + OUT_ZF  + (size_t)gb * Z_ + 0);
      __builtin_nontemporal_store(xn1, out + OUT_ZF  + (size_t)gb * Z_ + 1);
      __builtin_nontemporal_store(c0[(size_t)gb * Z_ + 0], out + OUT_CZF + (size_t)gb * Z_ + 0);
      __builtin_nontemporal_store(c0[(size_t)gb * Z_ + 1], out + OUT_CZF + (size_t)gb * Z_ + 1);
    }
  }
}

extern "C" void kernel_launch(void* const* d_in, const int* in_sizes, int n_in,
                              void* d_out, int out_size, void* d_ws, size_t ws_size,
                              hipStream_t stream) {
  const float* rnn  = (const float*)d_in[0];
  const float* tauP = (const float*)d_in[1];
  const float* z0   = (const float*)d_in[2];
  const float* c0   = (const float*)d_in[3];
  const float* wuw  = (const float*)d_in[4];
  const float* wub  = (const float*)d_in[5];
  const float* awp  = (const float*)d_in[6];
  const float* abp  = (const float*)d_in[7];
  const float* whw  = (const float*)d_in[8];
  const float* whb  = (const float*)d_in[9];
  const float* Amat = (const float*)d_in[10];
  const float* Bmat = (const float*)d_in[11];
  float* out = (float*)d_out;
  char* img = (char*)d_ws;   // 1 MB: 4 slots x 8 bg x 32KB

  // poison all image slots to 0xFFFF (f16 NaN sentinel) every call — part of the
  // captured graph, so every replay starts from the identical poisoned state
  hipMemsetAsync(d_ws, 0xFF, 4 * 8 * IMG_BYTES, stream);
  (void)in_sizes; (void)n_in; (void)out_size; (void)ws_size;

  hipLaunchKernelGGL(lstm_persist, dim3(256), dim3(512), 0, stream,
                     rnn, tauP, z0, c0, wuw, wub, awp, abp, whw, whb, Amat, Bmat,
                     out, img);
}